// Round 6
// baseline (164.574 us; speedup 1.0000x reference)
//
#include <hip/hip_runtime.h>

// NonLocalBlockND, algebraically collapsed (linear attention, no softmax):
//   A[b]    = g_p[b] . phi_p[b]^T / M                  [128,128]
//   W_big[b]= W_w . A[b] . W_theta                     [256,256]
//   b_eff[b]= W_w . (A[b] . b_theta) + b_w             [256]
//   out     = BN(W_big[b] . x + b_eff[b]) + x
//
// Round-6: r4 front-end (verified) + chain_kernel (g2+t1+wbig merged, LDS-
// resident intermediates) + final_kernel at 128x256 tiles (256 blocks, 1/CU).
//
// ws layout (bytes):
//   xT   [8][4096][256] bf16 @ 0          (16,777,216)
//   Wfg  [256][256]     bf16 @ 16777216   (   131,072)  rows 0-127 phi,128-255 g
//   phiT [8][128][1024] bf16 @ 16908288   ( 2,097,152)  pooled, [ci][m]
//   gT   [8][128][1024] bf16 @ 19005440   ( 2,097,152)  pooled, [ci][m]
//   Wbig [8][256][256]  bf16 @ 21102592   ( 1,048,576)
//   beff [8][256]       f32  @ 22151168   (     8,192)
// total 22,159,360 B

typedef __attribute__((ext_vector_type(8))) short bf16x8;
typedef __attribute__((ext_vector_type(4))) float f32x4;
typedef unsigned short u16;
typedef unsigned int u32;

constexpr int Cc = 256, NnC = 4096;
constexpr float kEps = 1e-5f;

__device__ __forceinline__ u16 f2b(float f) {
  u32 u = __float_as_uint(f);
  return (u16)((u + 0x7fffu + ((u >> 16) & 1u)) >> 16);
}
__device__ __forceinline__ float b2f(u16 h) {
  return __uint_as_float(((u32)h) << 16);
}
__device__ __forceinline__ u32 pack2(float a, float b) {
  return (u32)f2b(a) | ((u32)f2b(b) << 16);
}
__device__ __forceinline__ void gl16(const void* g, void* l) {
  __builtin_amdgcn_global_load_lds(
      (const __attribute__((address_space(1))) void*)g,
      (__attribute__((address_space(3))) void*)l, 16, 0, 0);
}

// ---------------------------------------------------------------------------
// prepw: stacked phi/g conv weights -> bf16 [256][256]   (r4-verified)
// ---------------------------------------------------------------------------
__global__ __launch_bounds__(256) void prepw_kernel(
    const float* __restrict__ wp, const float* __restrict__ wg,
    u16* __restrict__ Wfg) {
  const int idx = blockIdx.x * 256 + threadIdx.x;  // 65536
  const int r = idx >> 8, c = idx & 255;
  Wfg[idx] = f2b(r < 128 ? wp[r * 256 + c] : wg[(r - 128) * 256 + c]);
}

// ---------------------------------------------------------------------------
// prepx: transpose x [b][c][n] f32 -> xT [b][n][c] bf16.   (r4-verified)
// ---------------------------------------------------------------------------
__global__ __launch_bounds__(256) void prepx_kernel(const float* __restrict__ x,
                                                    u16* __restrict__ xT) {
  __shared__ float sm[64][65];
  const int b = blockIdx.z, c0 = blockIdx.y * 64, n0 = blockIdx.x * 64;
  const int tid = threadIdx.x;
  {
    const int n = tid & 63, cg = tid >> 6;
#pragma unroll
    for (int i = 0; i < 16; ++i) {
      const int c = cg * 16 + i;
      sm[c][n] = x[((size_t)(b * Cc + c0 + c)) * NnC + n0 + n];
    }
  }
  __syncthreads();
  {
    const int n = tid >> 2, q = tid & 3;
    u16 v[16];
#pragma unroll
    for (int j = 0; j < 16; ++j) v[j] = f2b(sm[q * 16 + j][n]);
    uint4 o0, o1;
    o0.x = v[0] | ((u32)v[1] << 16);
    o0.y = v[2] | ((u32)v[3] << 16);
    o0.z = v[4] | ((u32)v[5] << 16);
    o0.w = v[6] | ((u32)v[7] << 16);
    o1.x = v[8] | ((u32)v[9] << 16);
    o1.y = v[10] | ((u32)v[11] << 16);
    o1.z = v[12] | ((u32)v[13] << 16);
    o1.w = v[14] | ((u32)v[15] << 16);
    uint4* dst = (uint4*)(xT + ((size_t)(b * NnC + n0 + n)) * Cc + c0 + q * 16);
    dst[0] = o0;
    dst[1] = o1;
  }
}

// ---------------------------------------------------------------------------
// convfg: D[o][n] = Wfg[mt*128+o][:] . xT[n][:] (K=256).   (r4-verified)
// Epilogue: +bias, 2x2 maxpool, write [ci][m] to phiT (mt=0) or gT (mt=1).
// ---------------------------------------------------------------------------
__global__ __launch_bounds__(256) void convfg_kernel(
    const u16* __restrict__ xT, const u16* __restrict__ Wfg,
    const float* __restrict__ b_phi, const float* __restrict__ b_g,
    u16* __restrict__ phiT, u16* __restrict__ gT) {
  __shared__ u16 sm[2][2][8192];
  const int mt = blockIdx.x, nt = blockIdx.y, b = blockIdx.z;
  const int n0 = nt * 128;
  const int tid = threadIdx.x;
  const int w = tid >> 6, lane = tid & 63;
  const int r16 = lane & 15, kg = lane >> 4;
  const int oh = (w & 1) * 64, nh = (w >> 1) * 64;

  auto stage = [&](int buf, int k0) {
#pragma unroll
    for (int i = 0; i < 4; ++i) {
      const int lin = i * 4096 + tid * 16;
      const int row = lin >> 7, byte = lin & 127;
      gl16((const char*)Wfg + (size_t)(mt * 128 + row) * 512 + k0 * 2 +
               (byte ^ ((row & 7) << 4)),
           (char*)&sm[buf][0][0] + lin);
    }
#pragma unroll
    for (int i = 0; i < 4; ++i) {
      const int lin = i * 4096 + tid * 16;
      const int row = lin >> 7, byte = lin & 127;
      gl16((const char*)xT + ((size_t)(b * NnC + n0 + row) * Cc + k0) * 2 +
               (byte ^ ((row & 7) << 4)),
           (char*)&sm[buf][1][0] + lin);
    }
  };

  f32x4 acc[4][4];
#pragma unroll
  for (int i = 0; i < 4; ++i)
#pragma unroll
    for (int j = 0; j < 4; ++j) acc[i][j] = (f32x4)0.f;

  stage(0, 0);
  __syncthreads();
  for (int kt = 0; kt < 4; ++kt) {
    if (kt < 3) stage((kt + 1) & 1, (kt + 1) * 64);
    const char* A = (const char*)&sm[kt & 1][0][0];
    const char* Bm = (const char*)&sm[kt & 1][1][0];
#pragma unroll
    for (int ks = 0; ks < 2; ++ks) {
      bf16x8 af[4], bfr[4];
#pragma unroll
      for (int f = 0; f < 4; ++f) {
        const int o = oh + f * 16 + r16;
        af[f] = *(const bf16x8*)(A + ((o * 128 + ks * 64 + kg * 16) ^
                                      ((o & 7) << 4)));
        const int n = nh + f * 16 + r16;
        bfr[f] = *(const bf16x8*)(Bm + ((n * 128 + ks * 64 + kg * 16) ^
                                        ((n & 7) << 4)));
      }
#pragma unroll
      for (int fo = 0; fo < 4; ++fo)
#pragma unroll
        for (int fn = 0; fn < 4; ++fn)
          acc[fo][fn] = __builtin_amdgcn_mfma_f32_16x16x32_bf16(
              af[fo], bfr[fn], acc[fo][fn], 0, 0, 0);
    }
    __syncthreads();
  }

  const float* bias = (mt == 0) ? b_phi : b_g;
  u16* ldst = (u16*)&sm[0][0][0];
#pragma unroll
  for (int fo = 0; fo < 4; ++fo) {
    const int obase = oh + fo * 16 + kg * 4;
    const float b0 = bias[obase], b1 = bias[obase + 1], b2 = bias[obase + 2],
                b3 = bias[obase + 3];
#pragma unroll
    for (int fn = 0; fn < 4; ++fn) {
      const int n = nh + fn * 16 + r16;
      const f32x4 v = acc[fo][fn];
      uint2 p;
      p.x = pack2(v.x + b0, v.y + b1);
      p.y = pack2(v.z + b2, v.w + b3);
      *(uint2*)((char*)ldst + ((n * 256 + obase * 2) ^ ((n & 7) << 4))) = p;
    }
  }
  __syncthreads();

  u16* dst = (mt == 0) ? phiT : gT;
  const int ci = tid >> 1, half = tid & 1;
#pragma unroll
  for (int i = 0; i < 16; ++i) {
    const int mw = half * 16 + i;
    const int n00 = 2 * mw;
    float v0 = b2f(*(const u16*)((const char*)ldst +
                                 ((n00 * 256 + ci * 2) ^ ((n00 & 7) << 4))));
    float v1 = b2f(*(const u16*)((const char*)ldst +
                                 (((n00 + 1) * 256 + ci * 2) ^ (((n00 + 1) & 7) << 4))));
    float v2 = b2f(*(const u16*)((const char*)ldst +
                                 (((n00 + 64) * 256 + ci * 2) ^ (((n00 + 64) & 7) << 4))));
    float v3 = b2f(*(const u16*)((const char*)ldst +
                                 (((n00 + 65) * 256 + ci * 2) ^ (((n00 + 65) & 7) << 4))));
    const float mx = fmaxf(fmaxf(v0, v1), fmaxf(v2, v3));
    dst[((size_t)(b * 128 + ci)) * 1024 + nt * 32 + mw] = f2b(mx);
  }
}

// ---------------------------------------------------------------------------
// chain: per batch (grid=8, 512 thr): A = gT.phiT^T/M -> T1 = A.Wth ->
// Wbig = Ww.T1, beff = Ww.(A.bth)+b_w.  All intermediates in LDS.
// LDS: P0 [0,64K): ph1 dbuf / ph2 {wf f32 [128][68], WtT@36864} / ph3 WwS
//      P1 [64K,96K): Ab bf16 [128 ci][256B] swz (later v1 f32[128] at front)
//      P2 [96K,160K): T1s bf16 [256 j][256B] swz  ([j][ci], k=ci contig)
// ---------------------------------------------------------------------------
__global__ __launch_bounds__(512) void chain_kernel(
    const u16* __restrict__ phiT, const u16* __restrict__ gT,
    const float* __restrict__ w_theta, const float* __restrict__ w_w,
    const float* __restrict__ b_theta, const float* __restrict__ b_w,
    u16* __restrict__ Wbig, float* __restrict__ beff) {
  __shared__ __align__(16) char pool[163840];
  char* abp = pool + 65536;
  char* t1b = pool + 98304;
  const int b = blockIdx.x;
  const int t = threadIdx.x;
  const int w = t >> 6, lane = t & 63;
  const int r16 = lane & 15, kg = lane >> 4;
  const int cih = (w & 1) * 64;

  // ---- phase 1: A = gT . phiT^T / M   (K=1024, 16 chunks, dbuf) ----
  {
    const int cch = (w >> 1) * 32;
    auto stage1 = [&](int buf, int m0) {
      char* base = pool + buf * 32768;
#pragma unroll
      for (int i = 0; i < 2; ++i) {
        const int lin = i * 8192 + t * 16;
        const int row = lin >> 7, byte = lin & 127;
        gl16((const char*)gT + ((size_t)(b * 128 + row) * 1024 + m0) * 2 +
                 (byte ^ ((row & 7) << 4)),
             base + lin);
      }
#pragma unroll
      for (int i = 0; i < 2; ++i) {
        const int lin = i * 8192 + t * 16;
        const int row = lin >> 7, byte = lin & 127;
        gl16((const char*)phiT + ((size_t)(b * 128 + row) * 1024 + m0) * 2 +
                 (byte ^ ((row & 7) << 4)),
             base + 16384 + lin);
      }
    };
    f32x4 acc1[4][2];
#pragma unroll
    for (int i = 0; i < 4; ++i)
#pragma unroll
      for (int j = 0; j < 2; ++j) acc1[i][j] = (f32x4)0.f;
    stage1(0, 0);
    __syncthreads();
    for (int kt = 0; kt < 16; ++kt) {
      if (kt < 15) stage1((kt + 1) & 1, (kt + 1) * 64);
      const char* A = pool + (kt & 1) * 32768;
      const char* Bp = A + 16384;
#pragma unroll
      for (int ks = 0; ks < 2; ++ks) {
        bf16x8 af[4], bfr[2];
#pragma unroll
        for (int f = 0; f < 4; ++f) {
          const int o = cih + f * 16 + r16;
          af[f] = *(const bf16x8*)(A + ((o * 128 + ks * 64 + kg * 16) ^
                                        ((o & 7) << 4)));
        }
#pragma unroll
        for (int f = 0; f < 2; ++f) {
          const int lc = cch + f * 16 + r16;
          bfr[f] = *(const bf16x8*)(Bp + ((lc * 128 + ks * 64 + kg * 16) ^
                                          ((lc & 7) << 4)));
        }
#pragma unroll
        for (int fo = 0; fo < 4; ++fo)
#pragma unroll
          for (int fn = 0; fn < 2; ++fn)
            acc1[fo][fn] = __builtin_amdgcn_mfma_f32_16x16x32_bf16(
                af[fo], bfr[fn], acc1[fo][fn], 0, 0, 0);
      }
      __syncthreads();
    }
    // write A -> Ab bf16 swz, scaled 1/M
    constexpr float scl = 1.f / 1024.f;
#pragma unroll
    for (int fo = 0; fo < 4; ++fo)
#pragma unroll
      for (int fn = 0; fn < 2; ++fn)
#pragma unroll
        for (int r = 0; r < 4; ++r) {
          const int ci = cih + fo * 16 + kg * 4 + r;
          const int c = cch + fn * 16 + r16;
          *(u16*)(abp + ((ci * 256 + c * 2) ^ ((ci & 7) << 4))) =
              f2b(acc1[fo][fn][r] * scl);
        }
    __syncthreads();
  }

  // ---- phase 2: T1[ci][j] = sum_c Ab[ci][c]*Wth[c][j] -> T1s[j][ci] ----
  {
    float* wf = (float*)pool;       // [128][68] f32
    char* wtb = pool + 36864;       // [64 jl][128 c] bf16 swz
    const int jq = w >> 1;
    for (int j0 = 0; j0 < 256; j0 += 64) {
      {
        const int c2 = t >> 2, q = t & 3;
#pragma unroll
        for (int i = 0; i < 4; ++i) {
          const float4 v =
              *(const float4*)(w_theta + (size_t)c2 * 256 + j0 + q * 16 + i * 4);
          *(float4*)(wf + c2 * 68 + q * 16 + i * 4) = v;
        }
      }
      __syncthreads();
      {
        const int jl = t & 63, cg = t >> 6;
        float f[16];
#pragma unroll
        for (int k = 0; k < 16; ++k) f[k] = wf[(cg * 16 + k) * 68 + jl];
        uint4 p0, p1;
        p0.x = pack2(f[0], f[1]);
        p0.y = pack2(f[2], f[3]);
        p0.z = pack2(f[4], f[5]);
        p0.w = pack2(f[6], f[7]);
        p1.x = pack2(f[8], f[9]);
        p1.y = pack2(f[10], f[11]);
        p1.z = pack2(f[12], f[13]);
        p1.w = pack2(f[14], f[15]);
        *(uint4*)(wtb + ((jl * 256 + cg * 32) ^ ((jl & 7) << 4))) = p0;
        *(uint4*)(wtb + ((jl * 256 + cg * 32 + 16) ^ ((jl & 7) << 4))) = p1;
      }
      __syncthreads();
      f32x4 acc2[4];
#pragma unroll
      for (int i = 0; i < 4; ++i) acc2[i] = (f32x4)0.f;
#pragma unroll
      for (int ks = 0; ks < 4; ++ks) {
        bf16x8 af[4];
#pragma unroll
        for (int fo = 0; fo < 4; ++fo) {
          const int ci = cih + fo * 16 + r16;
          af[fo] = *(const bf16x8*)(abp + ((ci * 256 + ks * 64 + kg * 16) ^
                                           ((ci & 7) << 4)));
        }
        const int jl = jq * 16 + r16;
        const bf16x8 bfr = *(const bf16x8*)(wtb + ((jl * 256 + ks * 64 + kg * 16) ^
                                                   ((jl & 7) << 4)));
#pragma unroll
        for (int fo = 0; fo < 4; ++fo)
          acc2[fo] = __builtin_amdgcn_mfma_f32_16x16x32_bf16(af[fo], bfr,
                                                             acc2[fo], 0, 0, 0);
      }
      const int jg = j0 + jq * 16 + r16;
#pragma unroll
      for (int fo = 0; fo < 4; ++fo) {
        const int cib = cih + fo * 16 + kg * 4;
        uint2 p;
        p.x = pack2(acc2[fo][0], acc2[fo][1]);
        p.y = pack2(acc2[fo][2], acc2[fo][3]);
        *(uint2*)(t1b + ((jg * 256 + cib * 2) ^ ((jg & 7) << 4))) = p;
      }
      __syncthreads();
    }
  }

  // ---- phase 3: Wbig[o][j] = sum_ci Ww[o][ci]*T1[ci][j] ----
  {
    {  // load Ww f32 [256][128] -> bf16 swz at P0
      const int o = t >> 1, half = (t & 1) * 64;
#pragma unroll
      for (int j = 0; j < 8; ++j) {
        const float4 v0 = *(const float4*)(w_w + (size_t)o * 128 + half + j * 8);
        const float4 v1 =
            *(const float4*)(w_w + (size_t)o * 128 + half + j * 8 + 4);
        uint4 p;
        p.x = pack2(v0.x, v0.y);
        p.y = pack2(v0.z, v0.w);
        p.z = pack2(v1.x, v1.y);
        p.w = pack2(v1.z, v1.w);
        *(uint4*)(pool + ((o * 256 + (half + j * 8) * 2) ^ ((o & 7) << 4))) = p;
      }
    }
    __syncthreads();
    const int oq = (w & 3) * 64, jh = (w >> 2) * 128;
#pragma unroll
    for (int jp = 0; jp < 2; ++jp) {
      f32x4 acc3[4][4];
#pragma unroll
      for (int i = 0; i < 4; ++i)
#pragma unroll
        for (int j = 0; j < 4; ++j) acc3[i][j] = (f32x4)0.f;
#pragma unroll
      for (int ks = 0; ks < 4; ++ks) {
        bf16x8 af[4], bfr[4];
#pragma unroll
        for (int fo = 0; fo < 4; ++fo) {
          const int o = oq + fo * 16 + r16;
          af[fo] = *(const bf16x8*)(pool + ((o * 256 + ks * 64 + kg * 16) ^
                                            ((o & 7) << 4)));
        }
#pragma unroll
        for (int fn = 0; fn < 4; ++fn) {
          const int j = jh + jp * 64 + fn * 16 + r16;
          bfr[fn] = *(const bf16x8*)(t1b + ((j * 256 + ks * 64 + kg * 16) ^
                                            ((j & 7) << 4)));
        }
#pragma unroll
        for (int fo = 0; fo < 4; ++fo)
#pragma unroll
          for (int fn = 0; fn < 4; ++fn)
            acc3[fo][fn] = __builtin_amdgcn_mfma_f32_16x16x32_bf16(
                af[fo], bfr[fn], acc3[fo][fn], 0, 0, 0);
      }
#pragma unroll
      for (int fo = 0; fo < 4; ++fo)
#pragma unroll
        for (int fn = 0; fn < 4; ++fn)
#pragma unroll
          for (int r = 0; r < 4; ++r) {
            const int o = oq + fo * 16 + kg * 4 + r;
            const int j = jh + jp * 64 + fn * 16 + r16;
            Wbig[(size_t)b * 65536 + o * 256 + j] = f2b(acc3[fo][fn][r]);
          }
    }
  }

  // ---- beff = Ww.(A.bth) + b_w ----
  float vreg = 0.f;
  if (t < 128) {
    for (int c = 0; c < 128; ++c)
      vreg += b2f(*(const u16*)(abp + ((t * 256 + c * 2) ^ ((t & 7) << 4)))) *
              b_theta[c];
  }
  __syncthreads();
  if (t < 128) ((float*)abp)[t] = vreg;
  __syncthreads();
  if (t < 256) {
    float s = b_w[t];
    const float* v1 = (const float*)abp;
    for (int ci = 0; ci < 128; ++ci)
      s += b2f(*(const u16*)(pool + ((t * 256 + ci * 2) ^ ((t & 7) << 4)))) *
           v1[ci];
    beff[b * 256 + t] = s;
  }
}

// ---------------------------------------------------------------------------
// final: out[b][o][n] = BN(Wbig[b][o][:].xT[n][:] + beff) + x.  K=256.
// 512 thr, 128o x 256n tile, grid (2,16,8) = 256 blocks (1/CU), dbuf 96KB.
// ---------------------------------------------------------------------------
__global__ __launch_bounds__(512) void final_kernel(
    const u16* __restrict__ xT, const u16* __restrict__ Wbig,
    const float* __restrict__ beff, const float* __restrict__ gamma,
    const float* __restrict__ beta, const float* __restrict__ mean,
    const float* __restrict__ var, const float* __restrict__ x,
    float* __restrict__ out) {
  __shared__ __align__(16) char sm[2][49152];  // A 16KB @0, B 32KB @16384
  __shared__ float scs[128], offs[128];
  const int mt = blockIdx.x, nt = blockIdx.y, b = blockIdx.z;
  const int n0 = nt * 256;
  const int t = threadIdx.x;
  const int w = t >> 6, lane = t & 63;
  const int r16 = lane & 15, kg = lane >> 4;
  const int oh = (w & 1) * 64, nh = (w >> 1) * 64;

  if (t < 128) {
    const int o = mt * 128 + t;
    const float sc = gamma[o] * rsqrtf(var[o] + kEps);
    scs[t] = sc;
    offs[t] = beta[o] + (beff[b * 256 + o] - mean[o]) * sc;
  }

  auto stage = [&](int buf, int k0) {
#pragma unroll
    for (int i = 0; i < 2; ++i) {
      const int lin = i * 8192 + t * 16;
      const int row = lin >> 7, byte = lin & 127;
      gl16((const char*)Wbig + (size_t)b * 131072 +
               (size_t)(mt * 128 + row) * 512 + k0 * 2 +
               (byte ^ ((row & 7) << 4)),
           (char*)&sm[buf][0] + lin);
    }
#pragma unroll
    for (int i = 0; i < 4; ++i) {
      const int lin = i * 8192 + t * 16;
      const int row = lin >> 7, byte = lin & 127;
      gl16((const char*)xT + ((size_t)(b * NnC + n0 + row) * Cc + k0) * 2 +
               (byte ^ ((row & 7) << 4)),
           (char*)&sm[buf][16384] + lin);
    }
  };

  f32x4 acc[4][4];
#pragma unroll
  for (int i = 0; i < 4; ++i)
#pragma unroll
    for (int j = 0; j < 4; ++j) acc[i][j] = (f32x4)0.f;

  stage(0, 0);
  __syncthreads();
  for (int kt = 0; kt < 4; ++kt) {
    if (kt < 3) stage((kt + 1) & 1, (kt + 1) * 64);
    const char* A = (const char*)&sm[kt & 1][0];
    const char* Bm = A + 16384;
#pragma unroll
    for (int ks = 0; ks < 2; ++ks) {
      bf16x8 af[4], bfr[4];
#pragma unroll
      for (int f = 0; f < 4; ++f) {
        const int o = oh + f * 16 + r16;
        af[f] = *(const bf16x8*)(A + ((o * 128 + ks * 64 + kg * 16) ^
                                      ((o & 7) << 4)));
        const int n = nh + f * 16 + r16;
        bfr[f] = *(const bf16x8*)(Bm + ((n * 128 + ks * 64 + kg * 16) ^
                                        ((n & 7) << 4)));
      }
#pragma unroll
      for (int fo = 0; fo < 4; ++fo)
#pragma unroll
        for (int fn = 0; fn < 4; ++fn)
          acc[fo][fn] = __builtin_amdgcn_mfma_f32_16x16x32_bf16(
              af[fo], bfr[fn], acc[fo][fn], 0, 0, 0);
    }
    __syncthreads();
  }

  const size_t xb = ((size_t)b * Cc + mt * 128) * NnC;
#pragma unroll
  for (int fo = 0; fo < 4; ++fo) {
#pragma unroll
    for (int r = 0; r < 4; ++r) {
      const int ol = oh + fo * 16 + kg * 4 + r;
      const float sc = scs[ol], of = offs[ol];
      const size_t rowoff = xb + (size_t)ol * NnC + n0;
#pragma unroll
      for (int fn = 0; fn < 4; ++fn) {
        const int n = nh + fn * 16 + r16;
        out[rowoff + n] = fmaf(acc[fo][fn][r], sc, of) + x[rowoff + n];
      }
    }
  }
}

// ---------------------------------------------------------------------------
extern "C" void kernel_launch(void* const* d_in, const int* in_sizes, int n_in,
                              void* d_out, int out_size, void* d_ws,
                              size_t ws_size, hipStream_t stream) {
  const float* x = (const float*)d_in[0];
  const float* w_theta = (const float*)d_in[1];
  const float* b_theta = (const float*)d_in[2];
  const float* w_phi = (const float*)d_in[3];
  const float* b_phi = (const float*)d_in[4];
  const float* w_g = (const float*)d_in[5];
  const float* b_g = (const float*)d_in[6];
  const float* w_w = (const float*)d_in[7];
  const float* b_w = (const float*)d_in[8];
  const float* bn_gamma = (const float*)d_in[9];
  const float* bn_beta = (const float*)d_in[10];
  const float* bn_mean = (const float*)d_in[11];
  const float* bn_var = (const float*)d_in[12];
  float* out = (float*)d_out;

  char* ws = (char*)d_ws;
  u16* xT = (u16*)ws;
  u16* Wfg = (u16*)(ws + 16777216);
  u16* phiT = (u16*)(ws + 16908288);
  u16* gT = (u16*)(ws + 19005440);
  u16* Wbig = (u16*)(ws + 21102592);
  float* beff = (float*)(ws + 22151168);
  if (ws_size < 22159360ull) return;

  prepw_kernel<<<dim3(256), dim3(256), 0, stream>>>(w_phi, w_g, Wfg);
  prepx_kernel<<<dim3(64, 4, 8), dim3(256), 0, stream>>>(x, xT);
  convfg_kernel<<<dim3(2, 32, 8), dim3(256), 0, stream>>>(
      xT, Wfg, b_phi, b_g, phiT, gT);
  chain_kernel<<<dim3(8), dim3(512), 0, stream>>>(phiT, gT, w_theta, w_w,
                                                  b_theta, b_w, Wbig, beff);
  final_kernel<<<dim3(2, 16, 8), dim3(512), 0, stream>>>(
      xT, Wbig, beff, bn_gamma, bn_beta, bn_mean, bn_var, x, out);
}